// Round 3
// baseline (4305.462 us; speedup 1.0000x reference)
//
#include <hip/hip_runtime.h>
#include <math.h>

#define B 4
#define N 8192
#define K 1024
#define BN (B * N)
#define TPB 256
#define NBLK 1024              // grid size == exactly 4 blocks/CU * 256 CUs (co-resident)
#define NB_PER_B (NBLK / B)    // 256 chunks per batch
#define ROWS_A (K / NB_PER_B)  // 4 rows per block in row/argmax phases
#define COLS_B (N / NB_PER_B)  // 32 cols per block in col phase
#define WAVES (TPB / 64)       // 4

// Online lse in float: exp args are always <= 0 (no overflow); __expf(-inf)=0.
__device__ __forceinline__ void lse_step(float v, float& m, float& s) {
  float nm = fmaxf(m, v);
  s = s * __expf(m - nm) + __expf(v - nm);
  m = nm;
}
__device__ __forceinline__ void lse_merge(float m2, float s2, float& m, float& s) {
  float nm = fmaxf(m, m2);
  s = s * __expf(m - nm) + s2 * __expf(m2 - nm);
  m = nm;
}

// Device-scope grid barrier: count-up, phase target = gen*NBLK. Bounded spin so a
// co-residency failure degrades to a wrong answer instead of a hang.
__device__ __forceinline__ void gbar(unsigned* cnt, unsigned gen) {
  __threadfence();  // release: this thread's global writes -> device scope
  __syncthreads();
  if (threadIdx.x == 0) {
    __hip_atomic_fetch_add(cnt, 1u, __ATOMIC_RELEASE, __HIP_MEMORY_SCOPE_AGENT);
    unsigned target = gen * (unsigned)NBLK;
    int spins = 0;
    while (__hip_atomic_load(cnt, __ATOMIC_ACQUIRE, __HIP_MEMORY_SCOPE_AGENT) < target) {
      __builtin_amdgcn_s_sleep(8);
      if (++spins > 2000000) break;  // failsafe
    }
  }
  __syncthreads();
  __threadfence();  // acquire: invalidate stale cached lines before next phase reads
}

__global__ void init_kernel(unsigned* cnt) { *cnt = 0u; }

// Column pass: block owns cols [cc*32, cc*32+32) of batch b, reduces over all K rows.
// d[b,n] = -lse_k(g[b,k,n] - (sub ? rnew[b,k] : 0)).
// Thread map: cg=t&7 -> 4 cols (float4); rg=t>>3 (0..31); k = rg + 32*st, st=0..31.
// Per wave-inst: 8 rows x 128B contiguous = 1KB.
__device__ __forceinline__ void col_pass(const float* __restrict__ g,
                                         const float* __restrict__ rnew_g,
                                         float* __restrict__ d, float* rnew_s,
                                         float2 (*warr)[COLS_B], int b, int cc, int t,
                                         bool sub) {
  if (sub) {
    for (int i = t; i < K; i += TPB) rnew_s[i] = rnew_g[(size_t)b * K + i];
    __syncthreads();
  }
  const int cg = t & 7, rg = t >> 3;
  const int lane = t & 63, wv = t >> 6;
  const float* gp = g + ((size_t)(b * K + rg)) * N + cc * COLS_B + cg * 4;
  float m[4], s[4];
#pragma unroll
  for (int q = 0; q < 4; ++q) { m[q] = -INFINITY; s[q] = 0.f; }
  for (int st = 0; st < 32; ++st) {
    float4 gv = *(const float4*)(gp + (size_t)st * (32 * N));
    float rk = sub ? rnew_s[rg + 32 * st] : 0.f;
    lse_step(gv.x - rk, m[0], s[0]);
    lse_step(gv.y - rk, m[1], s[1]);
    lse_step(gv.z - rk, m[2], s[2]);
    lse_step(gv.w - rk, m[3], s[3]);
  }
  // merge the 8 rg-groups within the wave (lane bits 3,4,5)
#pragma unroll
  for (int off = 8; off <= 32; off <<= 1) {
#pragma unroll
    for (int q = 0; q < 4; ++q) {
      float m2 = __shfl_xor(m[q], off, 64);
      float s2 = __shfl_xor(s[q], off, 64);
      lse_merge(m2, s2, m[q], s[q]);
    }
  }
  if (lane < 8) {
#pragma unroll
    for (int q = 0; q < 4; ++q) warr[wv][cg * 4 + q] = make_float2(m[q], s[q]);
  }
  __syncthreads();
  if (t < COLS_B) {
    float mm = warr[0][t].x, ss = warr[0][t].y;
#pragma unroll
    for (int w = 1; w < WAVES; ++w) lse_merge(warr[w][t].x, warr[w][t].y, mm, ss);
    d[(size_t)b * N + cc * COLS_B + t] = -(mm + __logf(ss));
  }
}

// Row pass: block owns rows [cc*4, cc*4+4) of batch b, full N.
// rnew[b,k] = lse_n(g[b,k,:] + d[b,:]).
__device__ __forceinline__ void row_pass(const float* __restrict__ g,
                                         const float* __restrict__ d,
                                         float* __restrict__ rnew_g,
                                         float2 (*wpart)[WAVES], int b, int cc, int t) {
  const int lane = t & 63, wv = t >> 6;
  const float* dp = d + (size_t)b * N;
  float4 dv[8];
#pragma unroll
  for (int j = 0; j < 8; ++j) dv[j] = *(const float4*)(dp + j * 1024 + t * 4);
  const int k0 = cc * ROWS_A;
  for (int rI = 0; rI < ROWS_A; ++rI) {
    const float* gr = g + ((size_t)(b * K + k0 + rI)) * N;
    float m0 = -INFINITY, s0 = 0.f, m1 = -INFINITY, s1 = 0.f;
    float m2 = -INFINITY, s2 = 0.f, m3 = -INFINITY, s3 = 0.f;
#pragma unroll
    for (int j = 0; j < 8; ++j) {
      float4 gv = *(const float4*)(gr + j * 1024 + t * 4);
      lse_step(gv.x + dv[j].x, m0, s0);
      lse_step(gv.y + dv[j].y, m1, s1);
      lse_step(gv.z + dv[j].z, m2, s2);
      lse_step(gv.w + dv[j].w, m3, s3);
    }
    lse_merge(m1, s1, m0, s0);
    lse_merge(m3, s3, m2, s2);
    lse_merge(m2, s2, m0, s0);
#pragma unroll
    for (int off = 32; off; off >>= 1) {
      float mm = __shfl_down(m0, off, 64);
      float ss = __shfl_down(s0, off, 64);
      lse_merge(mm, ss, m0, s0);
    }
    if (lane == 0) wpart[rI][wv] = make_float2(m0, s0);
  }
  __syncthreads();
  if (t < ROWS_A) {
    float m = wpart[t][0].x, s = wpart[t][0].y;
#pragma unroll
    for (int w = 1; w < WAVES; ++w) lse_merge(wpart[t][w].x, wpart[t][w].y, m, s);
    rnew_g[(size_t)b * K + k0 + t] = m + __logf(s);
  }
}

// Argmax pass: wave wv handles row cc*4 + wv; first-index tie-breaking.
__device__ __forceinline__ void argmax_pass(const float* __restrict__ g,
                                            const float* __restrict__ d,
                                            float* __restrict__ out, int b, int cc,
                                            int t) {
  const int lane = t & 63, wv = t >> 6;
  const int k = cc * ROWS_A + wv;
  const float* gp = g + ((size_t)(b * K + k)) * N;
  const float* dp = d + (size_t)b * N;
  float bv = -INFINITY;
  int bi = 0;
#pragma unroll 4
  for (int j = 0; j < 32; ++j) {
    int n = j * 256 + lane * 4;
    float4 gv = *(const float4*)(gp + n);
    float4 dv = *(const float4*)(dp + n);
    float v;
    v = gv.x + dv.x; if (v > bv) { bv = v; bi = n + 0; }
    v = gv.y + dv.y; if (v > bv) { bv = v; bi = n + 1; }
    v = gv.z + dv.z; if (v > bv) { bv = v; bi = n + 2; }
    v = gv.w + dv.w; if (v > bv) { bv = v; bi = n + 3; }
  }
#pragma unroll
  for (int off = 32; off; off >>= 1) {
    float v2 = __shfl_down(bv, off, 64);
    int i2 = __shfl_down(bi, off, 64);
    if (v2 > bv || (v2 == bv && i2 < bi)) { bv = v2; bi = i2; }
  }
  if (lane == 0) {
    out[b * K + k] = 1.0f;                    // selected_scores (all-true mask)
    out[B * K + b * K + k] = (float)bi;       // selected_indices as float
  }
}

__global__ __launch_bounds__(TPB, 4) void sinkhorn_persistent(
    const float* __restrict__ g, float* __restrict__ d, float* __restrict__ rnew_g,
    unsigned* __restrict__ cnt, float* __restrict__ out) {
  __shared__ float rnew_s[K];                 // 4 KB
  __shared__ float2 warr[WAVES][COLS_B];      // 1 KB
  __shared__ float2 wpart[ROWS_A][WAVES];     // 128 B
  const int t = threadIdx.x;
  const int bid = blockIdx.x;
  const int b = bid >> 8;      // NB_PER_B == 256
  const int cc = bid & 255;
  unsigned gen = 0;

  // d1 = -lse_k(g)   (x, routing_token cancel: scores are constant along k and are
  // removed exactly by this first column logsumexp — only gumbel matters.)
  col_pass(g, rnew_g, d, rnew_s, warr, b, cc, t, false);
  gbar(cnt, ++gen);
  // iterations: r_i = lse_n(g + d_i); d_{i+1} = -lse_k(g - r_i)
  for (int it = 0; it < 7; ++it) {
    row_pass(g, d, rnew_g, wpart, b, cc, t);
    gbar(cnt, ++gen);
    col_pass(g, rnew_g, d, rnew_s, warr, b, cc, t, true);
    gbar(cnt, ++gen);
  }
  // 8th row update shifts each row uniformly -> argmax unaffected; skip it.
  argmax_pass(g, d, out, b, cc, t);
}

extern "C" void kernel_launch(void* const* d_in, const int* in_sizes, int n_in,
                              void* d_out, int out_size, void* d_ws, size_t ws_size,
                              hipStream_t stream) {
  const float* g = (const float*)d_in[2];
  float* out = (float*)d_out;

  char* ws = (char*)d_ws;
  unsigned* cnt = (unsigned*)ws;                       // 4 B barrier counter
  float* d = (float*)(ws + 4096);                      // 128 KB: per-column shift
  float* rnew_g = (float*)(ws + 4096 + (size_t)BN * 4);  // 16 KB: per-row shift

  init_kernel<<<1, 1, 0, stream>>>(cnt);
  sinkhorn_persistent<<<NBLK, TPB, 0, stream>>>(g, d, rnew_g, cnt, out);
}

// Round 5
// 1242.650 us; speedup vs baseline: 3.4647x; 3.4647x over previous
//
#include <hip/hip_runtime.h>
#include <math.h>

#define B 4
#define N 8192
#define K 1024
#define BN (B * N)
#define TPB 256
#define NBLK 1024              // exactly 4 blocks/CU * 256 CUs (co-resident by construction)
#define NB_PER_B (NBLK / B)    // 256 chunks per batch
#define ROWS_A (K / NB_PER_B)  // 4 rows per block in row/argmax phases
#define COLS_B (N / NB_PER_B)  // 32 cols per block in col phase
#define WAVES (TPB / 64)       // 4

typedef unsigned long long u64;

// ---- cross-XCD coherent access helpers (bypass stale per-XCD L2; served at L3) ----
__device__ __forceinline__ float2 cohload2(const float* p) {
  u64 v = __hip_atomic_load((const u64*)p, __ATOMIC_RELAXED, __HIP_MEMORY_SCOPE_AGENT);
  float2 r;
  r.x = __uint_as_float((unsigned)v);
  r.y = __uint_as_float((unsigned)(v >> 32));
  return r;
}
__device__ __forceinline__ void cohstore(float* p, float v) {
  __hip_atomic_store((unsigned*)p, __float_as_uint(v), __ATOMIC_RELAXED,
                     __HIP_MEMORY_SCOPE_AGENT);
}

// Online lse in float: exp args are always <= 0 (no overflow); __expf(-inf)=0.
__device__ __forceinline__ void lse_step(float v, float& m, float& s) {
  float nm = fmaxf(m, v);
  s = s * __expf(m - nm) + __expf(v - nm);
  m = nm;
}
__device__ __forceinline__ void lse_merge(float m2, float s2, float& m, float& s) {
  float nm = fmaxf(m, m2);
  s = s * __expf(m - nm) + s2 * __expf(m2 - nm);
  m = nm;
}

// Fence-free grid barrier. All cross-block data was written with agent-scope
// write-through atomics; __syncthreads' pre-barrier vmcnt drain guarantees those
// stores are at the coherence point before t0 publishes arrival. No __threadfence
// => no L2 wb/inv storm (the R3 4.3ms regression was 123k per-thread fence ops).
__device__ __forceinline__ void gbar(unsigned* cnt, unsigned gen) {
  __syncthreads();
  if (threadIdx.x == 0) {
    __hip_atomic_fetch_add(cnt, 1u, __ATOMIC_RELAXED, __HIP_MEMORY_SCOPE_AGENT);
    unsigned target = gen * (unsigned)NBLK;
    int spins = 0;
    while (__hip_atomic_load(cnt, __ATOMIC_RELAXED, __HIP_MEMORY_SCOPE_AGENT) < target) {
      __builtin_amdgcn_s_sleep(4);
      if (++spins > 5000000) break;  // failsafe: degrade to wrong answer, not hang
    }
  }
  __syncthreads();
}

__global__ void init_kernel(unsigned* cnt) { *cnt = 0u; }

// Column pass: block owns cols [cc*32, cc*32+32) of batch b, reduces over all K rows.
// d[b,n] = -lse_k(g[b,k,n] - (sub ? rnew[b,k] : 0)).
// Thread map: cg=t&7 -> 4 cols (float4); rg=t>>3 (0..31); k = rg + 32*st.
__device__ __forceinline__ void col_pass(const float* __restrict__ g,
                                         const float* __restrict__ rnew_g,
                                         float* __restrict__ d, float* rnew_s,
                                         float2 (*warr)[COLS_B], int b, int cc, int t,
                                         bool sub) {
  if (sub) {
    // stage rnew[b,:] (K floats) into LDS via coherent loads
    for (int i = t; i < K / 2; i += TPB) {
      float2 v = cohload2(rnew_g + (size_t)b * K + 2 * i);
      rnew_s[2 * i] = v.x;
      rnew_s[2 * i + 1] = v.y;
    }
    __syncthreads();
  }
  const int cg = t & 7, rg = t >> 3;
  const int lane = t & 63, wv = t >> 6;
  const float* gp = g + ((size_t)(b * K + rg)) * N + cc * COLS_B + cg * 4;
  float m[4], s[4];
#pragma unroll
  for (int q = 0; q < 4; ++q) { m[q] = -INFINITY; s[q] = 0.f; }
#pragma unroll 4
  for (int st = 0; st < 32; ++st) {
    float4 gv = *(const float4*)(gp + (size_t)st * (32 * N));
    float rk = sub ? rnew_s[rg + 32 * st] : 0.f;
    lse_step(gv.x - rk, m[0], s[0]);
    lse_step(gv.y - rk, m[1], s[1]);
    lse_step(gv.z - rk, m[2], s[2]);
    lse_step(gv.w - rk, m[3], s[3]);
  }
  // merge the 8 rg-groups within the wave (lane bits 3,4,5)
#pragma unroll
  for (int off = 8; off <= 32; off <<= 1) {
#pragma unroll
    for (int q = 0; q < 4; ++q) {
      float m2 = __shfl_xor(m[q], off, 64);
      float s2 = __shfl_xor(s[q], off, 64);
      lse_merge(m2, s2, m[q], s[q]);
    }
  }
  if (lane < 8) {
#pragma unroll
    for (int q = 0; q < 4; ++q) warr[wv][cg * 4 + q] = make_float2(m[q], s[q]);
  }
  __syncthreads();
  if (t < COLS_B) {
    float mm = warr[0][t].x, ss = warr[0][t].y;
#pragma unroll
    for (int w = 1; w < WAVES; ++w) lse_merge(warr[w][t].x, warr[w][t].y, mm, ss);
    cohstore(d + (size_t)b * N + cc * COLS_B + t, -(mm + __logf(ss)));
  }
  __syncthreads();
}

// Row pass: block owns rows [cc*4, cc*4+4) of batch b, full N.
// rnew[b,k] = lse_n(g[b,k,:] + d[b,:]).
__device__ __forceinline__ void row_pass(const float* __restrict__ g,
                                         const float* __restrict__ d,
                                         float* __restrict__ rnew_g,
                                         float2 (*wpart)[WAVES], int b, int cc, int t) {
  const int lane = t & 63, wv = t >> 6;
  const float* dp = d + (size_t)b * N;
  float4 dv[8];
#pragma unroll
  for (int j = 0; j < 8; ++j) {
    float2 a = cohload2(dp + j * 1024 + t * 4);
    float2 c = cohload2(dp + j * 1024 + t * 4 + 2);
    dv[j] = make_float4(a.x, a.y, c.x, c.y);
  }
  const int k0 = cc * ROWS_A;
  for (int rI = 0; rI < ROWS_A; ++rI) {
    const float* gr = g + ((size_t)(b * K + k0 + rI)) * N;
    float m0 = -INFINITY, s0 = 0.f, m1 = -INFINITY, s1 = 0.f;
    float m2 = -INFINITY, s2 = 0.f, m3 = -INFINITY, s3 = 0.f;
#pragma unroll
    for (int j = 0; j < 8; ++j) {
      float4 gv = *(const float4*)(gr + j * 1024 + t * 4);
      lse_step(gv.x + dv[j].x, m0, s0);
      lse_step(gv.y + dv[j].y, m1, s1);
      lse_step(gv.z + dv[j].z, m2, s2);
      lse_step(gv.w + dv[j].w, m3, s3);
    }
    lse_merge(m1, s1, m0, s0);
    lse_merge(m3, s3, m2, s2);
    lse_merge(m2, s2, m0, s0);
#pragma unroll
    for (int off = 32; off; off >>= 1) {
      float mm = __shfl_down(m0, off, 64);
      float ss = __shfl_down(s0, off, 64);
      lse_merge(mm, ss, m0, s0);
    }
    if (lane == 0) wpart[rI][wv] = make_float2(m0, s0);
  }
  __syncthreads();
  if (t < ROWS_A) {
    float m = wpart[t][0].x, s = wpart[t][0].y;
#pragma unroll
    for (int w = 1; w < WAVES; ++w) lse_merge(wpart[t][w].x, wpart[t][w].y, m, s);
    cohstore(rnew_g + (size_t)b * K + k0 + t, m + __logf(s));
  }
}

// Argmax pass: wave wv handles row cc*4 + wv; first-index tie-breaking.
// d staged into LDS via coherent loads (per-XCD L2 copies of d are stale).
__device__ __forceinline__ void argmax_pass(const float* __restrict__ g,
                                            const float* __restrict__ d, float* dsh,
                                            float* __restrict__ out, int b, int cc,
                                            int t) {
  const float* dp = d + (size_t)b * N;
  for (int i = t; i < N / 2; i += TPB) {
    float2 v = cohload2(dp + 2 * i);
    dsh[2 * i] = v.x;
    dsh[2 * i + 1] = v.y;
  }
  __syncthreads();
  const int lane = t & 63, wv = t >> 6;
  const int k = cc * ROWS_A + wv;
  const float* gp = g + ((size_t)(b * K + k)) * N;
  float bv = -INFINITY;
  int bi = 0;
#pragma unroll 4
  for (int j = 0; j < 32; ++j) {
    int n = j * 256 + lane * 4;
    float4 gv = *(const float4*)(gp + n);
    float4 dv = *(const float4*)(&dsh[n]);
    float v;
    v = gv.x + dv.x; if (v > bv) { bv = v; bi = n + 0; }
    v = gv.y + dv.y; if (v > bv) { bv = v; bi = n + 1; }
    v = gv.z + dv.z; if (v > bv) { bv = v; bi = n + 2; }
    v = gv.w + dv.w; if (v > bv) { bv = v; bi = n + 3; }
  }
#pragma unroll
  for (int off = 32; off; off >>= 1) {
    float v2 = __shfl_down(bv, off, 64);
    int i2 = __shfl_down(bi, off, 64);
    if (v2 > bv || (v2 == bv && i2 < bi)) { bv = v2; bi = i2; }
  }
  if (lane == 0) {
    out[b * K + k] = 1.0f;               // selected_scores (all-true mask)
    out[B * K + b * K + k] = (float)bi;  // selected_indices as float
  }
}

__global__ __launch_bounds__(TPB, 4) void sinkhorn_persistent(
    const float* __restrict__ g, float* __restrict__ d, float* __restrict__ rnew_g,
    unsigned* __restrict__ cnt, float* __restrict__ out) {
  __shared__ float sbuf[N];                // 32 KB; col_pass uses [0,K) for rnew stage,
                                           // argmax uses [0,N) for d stage
  __shared__ float2 warr[WAVES][COLS_B];   // 1 KB
  __shared__ float2 wpart[ROWS_A][WAVES];  // 128 B
  const int t = threadIdx.x;
  const int bid = blockIdx.x;
  const int b = bid >> 8;  // NB_PER_B == 256
  const int cc = bid & 255;
  unsigned gen = 0;

  // d1 = -lse_k(g)   (x, routing_token cancel: scores are constant along k and are
  // removed exactly by this first column logsumexp — only gumbel matters.)
  col_pass(g, rnew_g, d, sbuf, warr, b, cc, t, false);
  gbar(cnt, ++gen);
  // iterations: r_i = lse_n(g + d_i); d_{i+1} = -lse_k(g - r_i)
  for (int it = 0; it < 7; ++it) {
    row_pass(g, d, rnew_g, wpart, b, cc, t);
    gbar(cnt, ++gen);
    col_pass(g, rnew_g, d, sbuf, warr, b, cc, t, true);
    gbar(cnt, ++gen);
  }
  // 8th row update shifts each row uniformly -> argmax unaffected; skip it.
  argmax_pass(g, d, sbuf, out, b, cc, t);
}

extern "C" void kernel_launch(void* const* d_in, const int* in_sizes, int n_in,
                              void* d_out, int out_size, void* d_ws, size_t ws_size,
                              hipStream_t stream) {
  const float* g = (const float*)d_in[2];
  float* out = (float*)d_out;

  char* ws = (char*)d_ws;
  unsigned* cnt = (unsigned*)ws;                          // barrier counter
  float* d = (float*)(ws + 4096);                         // 128 KB per-column shift
  float* rnew_g = (float*)(ws + 4096 + (size_t)BN * 4);   // 16 KB per-row shift

  init_kernel<<<1, 1, 0, stream>>>(cnt);
  sinkhorn_persistent<<<NBLK, TPB, 0, stream>>>(g, d, rnew_g, cnt, out);
}

// Round 6
// 744.695 us; speedup vs baseline: 5.7815x; 1.6687x over previous
//
#include <hip/hip_runtime.h>
#include <math.h>

#define B 4
#define N 8192
#define K 1024
#define BN (B * N)
#define TPB 1024
#define NBLK 256              // 1 block/CU x 256 CUs; VGPR>64 guarantees 1/CU co-residency
#define RCH 8                 // rows per part-chunk
#define CPB (K / RCH)         // 128 chunks per batch
#define NCH (B * CPB)         // 512 chunks total

typedef unsigned long long u64;

// ---- cross-XCD coherent access (bypass per-XCD L2; write-through to L3) ----
__device__ __forceinline__ float2 cohload2(const float* p) {
  u64 v = __hip_atomic_load((const u64*)p, __ATOMIC_RELAXED, __HIP_MEMORY_SCOPE_AGENT);
  float2 r;
  r.x = __uint_as_float((unsigned)v);
  r.y = __uint_as_float((unsigned)(v >> 32));
  return r;
}
__device__ __forceinline__ void cohstore2(float* p, float a, float b) {
  u64 v = (u64)__float_as_uint(a) | ((u64)__float_as_uint(b) << 32);
  __hip_atomic_store((u64*)p, v, __ATOMIC_RELAXED, __HIP_MEMORY_SCOPE_AGENT);
}

// Online lse in float: exp args are always <= 0 (no overflow); __expf(-inf)=0.
__device__ __forceinline__ void lse_step(float v, float& m, float& s) {
  float nm = fmaxf(m, v);
  s = s * __expf(m - nm) + __expf(v - nm);
  m = nm;
}
__device__ __forceinline__ void lse_merge(float m2, float s2, float& m, float& s) {
  float nm = fmaxf(m, m2);
  s = s * __expf(m - nm) + s2 * __expf(m2 - nm);
  m = nm;
}

// Fence-free grid barrier (R5-proven): cross-block data uses agent-scope write-through
// atomics; __syncthreads' vmcnt drain puts them at the coherence point before t0
// publishes arrival. Bounded spin failsafe: degrade to wrong answer, never hang.
__device__ __forceinline__ void gbar(unsigned* cnt, unsigned gen) {
  __syncthreads();
  if (threadIdx.x == 0) {
    __hip_atomic_fetch_add(cnt, 1u, __ATOMIC_RELAXED, __HIP_MEMORY_SCOPE_AGENT);
    unsigned target = gen * (unsigned)NBLK;
    int spins = 0;
    while (__hip_atomic_load(cnt, __ATOMIC_RELAXED, __HIP_MEMORY_SCOPE_AGENT) < target) {
      __builtin_amdgcn_s_sleep(4);
      if (++spins > 5000000) break;
    }
  }
  __syncthreads();
}

__global__ void init_kernel(unsigned* cnt) { *cnt = 0u; }

// Phase A (the single g-sweep): block owns 16 rows (2 chunks of RCH=8) of batch b.
// For each 4-row register sub-chunk: [if SUB] r[row]=lse_n(g+d) via wave+LDS reduce,
// then col-partials lse_k(g - r) accumulate in regs (g reused from the SAME registers
// -> one memory read of g per iteration). part[chunk][n] written coherently.
template <bool SUB>
__device__ __forceinline__ void phaseA(const float* __restrict__ g,
                                       const float* __restrict__ d,
                                       float* __restrict__ part,
                                       float2 (*wpart)[16], float* rns, int b,
                                       int chunk0, int t) {
  const int lane = t & 63, wv = t >> 6;
  float4 dv[2];
  if (SUB) {
#pragma unroll
    for (int j = 0; j < 2; ++j) {
      const float* dp = d + (size_t)b * N + j * 4096 + t * 4;
      float2 a = cohload2(dp), c = cohload2(dp + 2);
      dv[j] = make_float4(a.x, a.y, c.x, c.y);
    }
  }
  for (int ci = 0; ci < 2; ++ci) {
    const int chunk = chunk0 + ci;
    const int k0 = (chunk & (CPB - 1)) * RCH;
    float cm[2][4], cs[2][4];
#pragma unroll
    for (int j = 0; j < 2; ++j)
#pragma unroll
      for (int q = 0; q < 4; ++q) { cm[j][q] = -INFINITY; cs[j][q] = 0.f; }
    for (int sc = 0; sc < 2; ++sc) {
      float4 gv[4][2];
#pragma unroll
      for (int r = 0; r < 4; ++r)
#pragma unroll
        for (int j = 0; j < 2; ++j)
          gv[r][j] =
              *(const float4*)(g + ((size_t)(b * K + k0 + sc * 4 + r)) * N + j * 4096 + t * 4);
      if (SUB) {
        // A1: per-row lse of g + d, 2-way ILP, 64-lane reduce, cross-wave via LDS
#pragma unroll
        for (int r = 0; r < 4; ++r) {
          float m0 = -INFINITY, s0 = 0.f, m1 = -INFINITY, s1 = 0.f;
          lse_step(gv[r][0].x + dv[0].x, m0, s0);
          lse_step(gv[r][0].y + dv[0].y, m1, s1);
          lse_step(gv[r][0].z + dv[0].z, m0, s0);
          lse_step(gv[r][0].w + dv[0].w, m1, s1);
          lse_step(gv[r][1].x + dv[1].x, m0, s0);
          lse_step(gv[r][1].y + dv[1].y, m1, s1);
          lse_step(gv[r][1].z + dv[1].z, m0, s0);
          lse_step(gv[r][1].w + dv[1].w, m1, s1);
          lse_merge(m1, s1, m0, s0);
#pragma unroll
          for (int off = 32; off; off >>= 1) {
            float mm = __shfl_down(m0, off, 64);
            float ss = __shfl_down(s0, off, 64);
            lse_merge(mm, ss, m0, s0);
          }
          if (lane == 0) wpart[r][wv] = make_float2(m0, s0);
        }
        __syncthreads();
        if (t < 64) {  // t = row*16 + wentry; merge 16 wave entries per row
          float2 e = wpart[t >> 4][t & 15];
          float m = e.x, s = e.y;
#pragma unroll
          for (int off = 1; off < 16; off <<= 1) {
            float mm = __shfl_xor(m, off, 64);
            float ss = __shfl_xor(s, off, 64);
            lse_merge(mm, ss, m, s);
          }
          if ((t & 15) == 0) rns[sc * 4 + (t >> 4)] = m + __logf(s);
        }
        __syncthreads();
      }
      // A2: col-partial accumulate from the SAME registers (no second g read)
#pragma unroll
      for (int r = 0; r < 4; ++r) {
        float rk = SUB ? rns[sc * 4 + r] : 0.f;
#pragma unroll
        for (int j = 0; j < 2; ++j) {
          lse_step(gv[r][j].x - rk, cm[j][0], cs[j][0]);
          lse_step(gv[r][j].y - rk, cm[j][1], cs[j][1]);
          lse_step(gv[r][j].z - rk, cm[j][2], cs[j][2]);
          lse_step(gv[r][j].w - rk, cm[j][3], cs[j][3]);
        }
      }
    }
    float* pp = part + (size_t)chunk * N;
#pragma unroll
    for (int j = 0; j < 2; ++j) {
      float o0 = cm[j][0] + __logf(cs[j][0]);
      float o1 = cm[j][1] + __logf(cs[j][1]);
      float o2 = cm[j][2] + __logf(cs[j][2]);
      float o3 = cm[j][3] + __logf(cs[j][3]);
      cohstore2(pp + j * 4096 + t * 4, o0, o1);
      cohstore2(pp + j * 4096 + t * 4 + 2, o2, o3);
    }
  }
}

// Phase B (tiny): fold CPB=128 chunk-partials per column -> d[b,n] = -lse.
// Block owns 128 consecutive cols of one batch; 16 p-groups x 8 chunks each + LDS merge.
__device__ __forceinline__ void phaseB(const float* __restrict__ part,
                                       float* __restrict__ d, float4 (*redB)[64],
                                       int cb, int n0, int t) {
  const int pg = t >> 6, cidx = t & 63;
  const float* pp = part + (size_t)(cb * CPB + pg * 8) * N + n0 + cidx * 2;
  float m0 = -INFINITY, s0 = 0.f, m1 = -INFINITY, s1 = 0.f;
#pragma unroll
  for (int i = 0; i < 8; ++i) {
    float2 v = cohload2(pp + (size_t)i * N);
    lse_step(v.x, m0, s0);
    lse_step(v.y, m1, s1);
  }
  redB[pg][cidx] = make_float4(m0, s0, m1, s1);
  __syncthreads();
  if (t < 64) {
    float4 a = redB[0][t];
    float mm0 = a.x, ss0 = a.y, mm1 = a.z, ss1 = a.w;
#pragma unroll
    for (int w = 1; w < 16; ++w) {
      float4 e = redB[w][t];
      lse_merge(e.x, e.y, mm0, ss0);
      lse_merge(e.z, e.w, mm1, ss1);
    }
    cohstore2(d + (size_t)cb * N + n0 + t * 2, -(mm0 + __logf(ss0)), -(mm1 + __logf(ss1)));
  }
}

// Argmax: wave wv handles one of the block's 16 rows; d staged into LDS coherently.
__device__ __forceinline__ void argmax_pass(const float* __restrict__ g,
                                            const float* __restrict__ d, float* dsh,
                                            float* __restrict__ out, int b, int chunk0,
                                            int t) {
  const float* dp = d + (size_t)b * N;
  for (int i = t; i < N / 2; i += TPB) {
    float2 v = cohload2(dp + 2 * i);
    dsh[2 * i] = v.x;
    dsh[2 * i + 1] = v.y;
  }
  __syncthreads();
  const int lane = t & 63, wv = t >> 6;
  const int chunk = chunk0 + (wv >> 3);
  const int k = (chunk & (CPB - 1)) * RCH + (wv & 7);
  const float* gp = g + ((size_t)(b * K + k)) * N;
  float bv = -INFINITY;
  int bi = 0;
#pragma unroll 4
  for (int j = 0; j < 32; ++j) {
    int n = j * 256 + lane * 4;
    float4 gv = *(const float4*)(gp + n);
    float4 dv = *(const float4*)(&dsh[n]);
    float v;
    v = gv.x + dv.x; if (v > bv) { bv = v; bi = n + 0; }
    v = gv.y + dv.y; if (v > bv) { bv = v; bi = n + 1; }
    v = gv.z + dv.z; if (v > bv) { bv = v; bi = n + 2; }
    v = gv.w + dv.w; if (v > bv) { bv = v; bi = n + 3; }
  }
#pragma unroll
  for (int off = 32; off; off >>= 1) {
    float v2 = __shfl_down(bv, off, 64);
    int i2 = __shfl_down(bi, off, 64);
    if (v2 > bv || (v2 == bv && i2 < bi)) { bv = v2; bi = i2; }
  }
  if (lane == 0) {
    out[b * K + k] = 1.0f;               // selected_scores (all-true mask)
    out[B * K + b * K + k] = (float)bi;  // selected_indices as float
  }
}

__global__ __launch_bounds__(TPB, 4) void sinkhorn_persistent(
    const float* __restrict__ g, float* __restrict__ d, float* __restrict__ part,
    unsigned* __restrict__ cnt, float* __restrict__ out) {
  __shared__ float2 wpart[4][16];   // 512 B
  __shared__ float rns[8];          // 32 B
  __shared__ float4 redB[16][64];   // 16 KB
  __shared__ float dsh[N];          // 32 KB (argmax only)
  const int t = threadIdx.x, bid = blockIdx.x;
  const int chunk0 = bid * 2;       // both chunks in the same batch (128 chunks/batch even)
  const int rb = chunk0 >> 7;       // batch for row phases
  const int cb = bid >> 6;          // batch for phase B
  const int n0 = (bid & 63) * 128;  // column base for phase B
  unsigned gen = 0;

  // iter 1 col-update: d1 = -lse_k(g)   (x, routing_token cancel: scores are constant
  // along k, removed exactly by this first column logsumexp — only gumbel matters.)
  phaseA<false>(g, d, part, wpart, rns, rb, chunk0, t);
  gbar(cnt, ++gen);
  phaseB(part, d, redB, cb, n0, t);
  gbar(cnt, ++gen);
  // iters 2..8: r_i = lse_n(g + d_i) (block-local!); d_{i+1} = -lse_k(g - r_i)
  for (int it = 0; it < 7; ++it) {
    phaseA<true>(g, d, part, wpart, rns, rb, chunk0, t);
    gbar(cnt, ++gen);
    phaseB(part, d, redB, cb, n0, t);
    gbar(cnt, ++gen);
  }
  // 8th row update shifts each row uniformly -> argmax unaffected; skip it.
  argmax_pass(g, d, dsh, out, rb, chunk0, t);
}

extern "C" void kernel_launch(void* const* d_in, const int* in_sizes, int n_in,
                              void* d_out, int out_size, void* d_ws, size_t ws_size,
                              hipStream_t stream) {
  const float* g = (const float*)d_in[2];
  float* out = (float*)d_out;

  char* ws = (char*)d_ws;
  unsigned* cnt = (unsigned*)ws;             // barrier counter
  float* d = (float*)(ws + 4096);            // 128 KB: per-column shift
  float* part = (float*)(ws + (1 << 20));    // 16 MB: NCH x N chunk col-partials

  init_kernel<<<1, 1, 0, stream>>>(cnt);
  sinkhorn_persistent<<<NBLK, TPB, 0, stream>>>(g, d, part, cnt, out);
}

// Round 17
// 613.076 us; speedup vs baseline: 7.0227x; 1.2147x over previous
//
#include <hip/hip_runtime.h>
#include <math.h>

#define B 4
#define N 8192
#define K 1024
#define BN (B * N)
#define RCH 8             // rows per chunk/block in sweepA
#define CPB (K / RCH)     // 128 chunks per batch
#define NCHK (B * CPB)    // 512 chunks total = sweepA grid
#define TPA 1024          // sweepA threads; 8 floats per thread per row

// Online lse in float: exp args are always <= 0 (no overflow); __expf(-inf)=0.
__device__ __forceinline__ void lse_step(float v, float& m, float& s) {
  float nm = fmaxf(m, v);
  s = s * __expf(m - nm) + __expf(v - nm);
  m = nm;
}
__device__ __forceinline__ void lse_merge(float m2, float s2, float& m, float& s) {
  float nm = fmaxf(m, m2);
  s = s * __expf(m - nm) + s2 * __expf(m2 - nm);
  m = nm;
}

// One g-sweep per Sinkhorn iteration (R6 algorithm, multi-kernel form).
// Block owns RCH=8 full rows of batch b. Per 4-row register sub-chunk:
//   [SUB] A1: r[row] = lse_n(g + d) via wave shfl + LDS cross-wave reduce (block-local!)
//   A2: col-partials lse_k(g - r) accumulated from the SAME registers -> one g read.
// part[(b*CPB+ci)*N + n] = lse over this chunk's 8 rows. Plain cached stores;
// kernel-boundary coherence. (Device-fn template wrapped by plain-named __global__
// kernels: identical codegen, avoids templated kernel names in harness/rocprof.)
template <bool SUB>
__device__ __forceinline__ void sweepA_body(const float* __restrict__ g,
                                            const float* __restrict__ d,
                                            float* __restrict__ part) {
  __shared__ float2 wpart[4][16];  // [row in sub-chunk][wave]
  __shared__ float rns[8];         // r for the 8 rows
  const int blk = blockIdx.x;
  const int b = blk >> 7;  // CPB == 128
  const int k0 = (blk & (CPB - 1)) * RCH;
  const int t = threadIdx.x, lane = t & 63, wv = t >> 6;
  const float* gbase = g + ((size_t)(b * K + k0)) * N;

  float4 dv[2];
  if (SUB) {
#pragma unroll
    for (int j = 0; j < 2; ++j)
      dv[j] = *(const float4*)(d + (size_t)b * N + j * 4096 + t * 4);
  }
  float cm[2][4], cs[2][4];
#pragma unroll
  for (int j = 0; j < 2; ++j)
#pragma unroll
    for (int q = 0; q < 4; ++q) { cm[j][q] = -INFINITY; cs[j][q] = 0.f; }

#pragma unroll
  for (int sc = 0; sc < 2; ++sc) {
    float4 gv[4][2];
#pragma unroll
    for (int r = 0; r < 4; ++r)
#pragma unroll
      for (int j = 0; j < 2; ++j)
        gv[r][j] = *(const float4*)(gbase + (size_t)(sc * 4 + r) * N + j * 4096 + t * 4);
    if (SUB) {
      // A1: per-row lse of g + d (2-way ILP), 64-lane reduce, cross-wave via LDS
#pragma unroll
      for (int r = 0; r < 4; ++r) {
        float m0 = -INFINITY, s0 = 0.f, m1 = -INFINITY, s1 = 0.f;
        lse_step(gv[r][0].x + dv[0].x, m0, s0);
        lse_step(gv[r][0].y + dv[0].y, m1, s1);
        lse_step(gv[r][0].z + dv[0].z, m0, s0);
        lse_step(gv[r][0].w + dv[0].w, m1, s1);
        lse_step(gv[r][1].x + dv[1].x, m0, s0);
        lse_step(gv[r][1].y + dv[1].y, m1, s1);
        lse_step(gv[r][1].z + dv[1].z, m0, s0);
        lse_step(gv[r][1].w + dv[1].w, m1, s1);
        lse_merge(m1, s1, m0, s0);
#pragma unroll
        for (int off = 32; off; off >>= 1) {
          float mm = __shfl_down(m0, off, 64);
          float ss = __shfl_down(s0, off, 64);
          lse_merge(mm, ss, m0, s0);
        }
        if (lane == 0) wpart[r][wv] = make_float2(m0, s0);
      }
      __syncthreads();
      if (t < 64) {  // t = row*16 + wentry; merge 16 wave entries per row
        float2 e = wpart[t >> 4][t & 15];
        float m = e.x, s = e.y;
#pragma unroll
        for (int off = 1; off < 16; off <<= 1) {
          float mm = __shfl_xor(m, off, 64);
          float ss = __shfl_xor(s, off, 64);
          lse_merge(mm, ss, m, s);
        }
        if ((t & 15) == 0) rns[sc * 4 + (t >> 4)] = m + __logf(s);
      }
      __syncthreads();
    }
    // A2: col-partial accumulate from the SAME registers (no second g read)
#pragma unroll
    for (int r = 0; r < 4; ++r) {
      float rk = SUB ? rns[sc * 4 + r] : 0.f;
#pragma unroll
      for (int j = 0; j < 2; ++j) {
        lse_step(gv[r][j].x - rk, cm[j][0], cs[j][0]);
        lse_step(gv[r][j].y - rk, cm[j][1], cs[j][1]);
        lse_step(gv[r][j].z - rk, cm[j][2], cs[j][2]);
        lse_step(gv[r][j].w - rk, cm[j][3], cs[j][3]);
      }
    }
  }
  float* pp = part + (size_t)blk * N;
#pragma unroll
  for (int j = 0; j < 2; ++j) {
    float4 o = make_float4(cm[j][0] + __logf(cs[j][0]), cm[j][1] + __logf(cs[j][1]),
                           cm[j][2] + __logf(cs[j][2]), cm[j][3] + __logf(cs[j][3]));
    *(float4*)(pp + j * 4096 + t * 4) = o;
  }
}

__global__ __launch_bounds__(TPA) void sweepA0_kernel(const float* __restrict__ g,
                                                      const float* __restrict__ d,
                                                      float* __restrict__ part) {
  sweepA_body<false>(g, d, part);
}
__global__ __launch_bounds__(TPA) void sweepA1_kernel(const float* __restrict__ g,
                                                      const float* __restrict__ d,
                                                      float* __restrict__ part) {
  sweepA_body<true>(g, d, part);
}

// Fold CPB=128 chunk-partials per column -> d[b*N+n] = -lse_k(...).
// 8 p-groups x 16 chunks each + LDS merge (R2-proven shape, new part layout).
__global__ __launch_bounds__(256) void sweepB_kernel(const float* __restrict__ part,
                                                     float* __restrict__ d) {
  int c = threadIdx.x & 31;   // column within block
  int pg = threadIdx.x >> 5;  // p-group 0..7
  int idx = blockIdx.x * 32 + c;  // b*N + n
  int b = idx >> 13;              // N == 8192
  int n = idx & (N - 1);
  const float* pp = part + ((size_t)(b * CPB + pg * 16)) * N + n;
  float m = -INFINITY, s = 0.f;
#pragma unroll
  for (int i = 0; i < 16; ++i) lse_step(pp[(size_t)i * N], m, s);
  __shared__ float2 red[8][32];
  red[pg][c] = make_float2(m, s);
  __syncthreads();
  if (threadIdx.x < 32) {
    float mm = red[0][threadIdx.x].x, ss = red[0][threadIdx.x].y;
#pragma unroll
    for (int w = 1; w < 8; ++w)
      lse_merge(red[w][threadIdx.x].x, red[w][threadIdx.x].y, mm, ss);
    d[blockIdx.x * 32 + threadIdx.x] = -(mm + __logf(ss));
  }
}

// out[row] = 1.0; out[B*K+row] = argmax_n(g[row,:] + d[b,:]) (first-index ties)
__global__ __launch_bounds__(256) void argmax_kernel(const float* __restrict__ g,
                                                     const float* __restrict__ d,
                                                     float* __restrict__ out) {
  int row = blockIdx.x;  // b*K + k
  int b = row >> 10;
  const float* gp = g + (size_t)row * N;
  const float* dp = d + b * N;
  float bv = -INFINITY;
  int bi = 0;
#pragma unroll
  for (int j = 0; j < 8; ++j) {
    int n = j * 1024 + threadIdx.x * 4;
    float4 gv = *(const float4*)(gp + n);
    float4 dv = *(const float4*)(dp + n);
    float v;
    v = gv.x + dv.x; if (v > bv) { bv = v; bi = n + 0; }
    v = gv.y + dv.y; if (v > bv) { bv = v; bi = n + 1; }
    v = gv.z + dv.z; if (v > bv) { bv = v; bi = n + 2; }
    v = gv.w + dv.w; if (v > bv) { bv = v; bi = n + 3; }
  }
  __shared__ float svv[256];
  __shared__ int sii[256];
  svv[threadIdx.x] = bv;
  sii[threadIdx.x] = bi;
  __syncthreads();
  for (int off = 128; off > 0; off >>= 1) {
    if (threadIdx.x < off) {
      float v2 = svv[threadIdx.x + off];
      int i2 = sii[threadIdx.x + off];
      float v1 = svv[threadIdx.x];
      int i1 = sii[threadIdx.x];
      if (v2 > v1 || (v2 == v1 && i2 < i1)) {
        svv[threadIdx.x] = v2;
        sii[threadIdx.x] = i2;
      }
    }
    __syncthreads();
  }
  if (threadIdx.x == 0) {
    out[row] = 1.0f;                   // selected_scores forward value (all-true mask)
    out[B * K + row] = (float)sii[0];  // selected_indices as float
  }
}

extern "C" void kernel_launch(void* const* d_in, const int* in_sizes, int n_in,
                              void* d_out, int out_size, void* d_ws, size_t ws_size,
                              hipStream_t stream) {
  // x, routing_token cancel out of the forward outputs (scores constant along k,
  // removed exactly by the first column logsumexp). Only gumbel matters.
  const float* g = (const float*)d_in[2];
  float* out = (float*)d_out;

  char* ws = (char*)d_ws;
  float* d = (float*)ws;                    // 128 KB: d[b*N+n] = -lse_k(...)
  float* part = (float*)(ws + (1 << 20));   // 16 MB: NCHK x N chunk col-partials

  // iter 1 col-update: d1 = -lse_k(g)
  sweepA0_kernel<<<NCHK, TPA, 0, stream>>>(g, d, part);
  sweepB_kernel<<<BN / 32, 256, 0, stream>>>(part, d);
  // iters 2..8: r_i = lse_n(g + d_i) block-local; d_{i+1} = -lse_k(g - r_i)
  for (int it = 0; it < 7; ++it) {
    sweepA1_kernel<<<NCHK, TPA, 0, stream>>>(g, d, part);
    sweepB_kernel<<<BN / 32, 256, 0, stream>>>(part, d);
  }
  // 8th row update shifts each row uniformly -> argmax unaffected; skip it.
  argmax_kernel<<<B * K, 256, 0, stream>>>(g, d, out);
}